// Round 6
// baseline (3259.832 us; speedup 1.0000x reference)
//
#include <hip/hip_runtime.h>
#include <math.h>

#define N      100   // nodes per problem
#define D      128   // embedding dim = H*DKH
#define KL     10    // prefix length
#define S0     90    // unvisited slots (fixed)
#define STEPS  90
#define LDK    132   // LDS row stride (floats); odd float4 count
#define NT     512

__device__ __forceinline__ float dot4(float4 a, float4 b) {
  return a.x*b.x + a.y*b.y + a.z*b.z + a.w*b.w;
}
__device__ __forceinline__ void fma4(float4& acc, float a, float4 v) {
  acc.x += a*v.x; acc.y += a*v.y; acc.z += a*v.z; acc.w += a*v.w;
}

// Rows [base, base+cnt) of E@W (col-major W) or Wcomb (row-major) -> stage[row*LDK+col].
// RPT bounds the per-call register working set (acc[RPT]+nd[RPT]+w[16]).
template<int RPT>
__device__ __forceinline__ void cc(const float* __restrict__ encB,
                                   const float* __restrict__ W,
                                   bool wRowMajor, int base, int cnt,
                                   const int* __restrict__ slotNode,
                                   float* __restrict__ stage, int tid) {
  const int col = tid & 127;
  const int grp = tid >> 7;
  float acc[RPT];
  int   nd [RPT];
  #pragma unroll
  for (int ii = 0; ii < RPT; ++ii) {
    acc[ii] = 0.f;
    int r = grp + 4*ii;
    nd[ii] = (r < cnt) ? __builtin_amdgcn_readfirstlane(slotNode[base + r]) : 0;
  }
  for (int dd = 0; dd < D; dd += 16) {
    float w[16];
    #pragma unroll
    for (int t = 0; t < 16; ++t)
      w[t] = wRowMajor ? W[col*D + dd + t] : W[(dd+t)*D + col];
    #pragma unroll
    for (int ii = 0; ii < RPT; ++ii) {
      int r = grp + 4*ii;
      if (r < cnt) {
        const float* er = encB + (size_t)nd[ii]*D + dd;
        float a0=0,a1=0,a2=0,a3=0;
        #pragma unroll
        for (int t = 0; t < 16; t += 4) {
          a0 += er[t]*w[t];   a1 += er[t+1]*w[t+1];
          a2 += er[t+2]*w[t+2]; a3 += er[t+3]*w[t+3];
        }
        acc[ii] += (a0+a1)+(a2+a3);
      }
    }
  }
  #pragma unroll
  for (int ii = 0; ii < RPT; ++ii) {
    int r = grp + 4*ii;
    if (r < cnt) stage[(base + r)*LDK + col] = acc[ii];
  }
}

// NOTE: this compiler's __launch_bounds__ 2nd arg is MIN BLOCKS PER CU (CUDA
// semantics), NOT waves/EU: (512,4) produced a 64-VGPR cap (=4 blocks/CU) and
// massive scratch spills (R4/R5: WRITE_SIZE 115-225 MB). (512,2) => 128 VGPRs.
__global__ __launch_bounds__(NT, 2)
void policy_kernel(const float* __restrict__ enc,
                   const float* __restrict__ Wq_first,
                   const float* __restrict__ Wq_last,
                   const float* __restrict__ Wk,
                   const float* __restrict__ Wv,
                   const float* __restrict__ Wcomb,
                   const int*   __restrict__ prefix,
                   int*         __restrict__ out) {
  // ---- LDS ~52 KB -> 2 blocks/CU ----
  __shared__ __align__(16) float sCE[S0*LDK];  // 47.5 KB: staging for K,V; final CE home
  __shared__ __align__(16) float sq[D];        // current q row
  __shared__ __align__(16) float sAtt[8*96];   // exp(score), pad rows 90..95 = 0
  __shared__ __align__(16) float sMh[D];       // q1 scratch, then normalized mh
  __shared__ float sSum[8];
  __shared__ int   sSlotNode[96];
  __shared__ unsigned long long sPacked[2];    // double-buffered argmax
  __shared__ int   sLast0;

  const int tid = threadIdx.x;
  const int b   = blockIdx.x;
  const float* encB = enc + (size_t)b*N*D;

  // ---- init ----
  if (tid < KL) out[(size_t)b*N + tid] = prefix[b*KL + tid];
  if (tid < 48) sAtt[(tid/6)*96 + 90 + (tid%6)] = 0.f;   // pad entries read by C
  if (tid == 0) {
    unsigned vis[4] = {0u,0u,0u,0u};
    const int* pr = prefix + b*KL;
    for (int j = 0; j < KL; ++j) { int n = pr[j]; vis[n>>5] |= 1u << (n&31); }
    int cnt = 0;
    for (int n = 0; n < N; ++n)
      if (!((vis[n>>5] >> (n&31)) & 1u)) sSlotNode[cnt++] = n;
    sLast0 = pr[KL-1];
    sPacked[0] = 0ull; sPacked[1] = 0ull;
  }
  __syncthreads();

  // ---- q1 = enc[last0] @ Wq_first -> sMh (scratch) ----
  if (tid < D) {
    const int last0 = sLast0;
    const float* er = encB + (size_t)last0*D;
    float a0=0,a1=0,a2=0,a3=0;
    #pragma unroll
    for (int d = 0; d < D; d += 4) {
      a0 += er[d]  *Wq_first[d*D     + tid];
      a1 += er[d+1]*Wq_first[(d+1)*D + tid];
      a2 += er[d+2]*Wq_first[(d+2)*D + tid];
      a3 += er[d+3]*Wq_first[(d+3)*D + tid];
    }
    sMh[tid] = (a0+a1)+(a2+a3);
  }
  __syncthreads();

  // ---- qP rows in REGISTERS: qp[ii] = q1[col] + (enc[row]@Wq_last)[col], row=grp+4*ii ----
  const int col = tid & 127;
  const int grp = tid >> 7;
  float qp[23];
  {
    int nd[23];
    #pragma unroll
    for (int ii = 0; ii < 23; ++ii) {
      int r = grp + 4*ii;
      nd[ii] = (r < S0) ? __builtin_amdgcn_readfirstlane(sSlotNode[r])
                        : ((r == S0) ? sLast0 : 0);
      qp[ii] = 0.f;
    }
    for (int dd = 0; dd < D; dd += 16) {
      float w[16];
      #pragma unroll
      for (int t = 0; t < 16; ++t) w[t] = Wq_last[(dd+t)*D + col];
      #pragma unroll
      for (int ii = 0; ii < 23; ++ii) {
        int r = grp + 4*ii;
        if (r <= S0) {
          const float* er = encB + (size_t)nd[ii]*D + dd;
          float a0=0,a1=0,a2=0,a3=0;
          #pragma unroll
          for (int t = 0; t < 16; t += 4) {
            a0 += er[t]*w[t];   a1 += er[t+1]*w[t+1];
            a2 += er[t+2]*w[t+2]; a3 += er[t+3]*w[t+3];
          }
          qp[ii] += (a0+a1)+(a2+a3);
        }
      }
    }
    const float q1c = sMh[col];
    #pragma unroll
    for (int ii = 0; ii < 23; ++ii) qp[ii] += q1c;
  }

  const int h = tid >> 6, l = tid & 63;

  // ---- K pass: stage all 90 rows, load per-lane fragments ----
  cc<23>(encB, Wk, false, 0, S0, sSlotNode, sCE, tid);
  __syncthreads();
  float4 ka0,ka1,ka2,ka3, kb0,kb1,kb2,kb3;
  {
    const float* p = &sCE[l*LDK + h*16];
    ka0 = *(const float4*)(p+0);  ka1 = *(const float4*)(p+4);
    ka2 = *(const float4*)(p+8);  ka3 = *(const float4*)(p+12);
  }
  if (l < 26) {
    const float* p = &sCE[(64+l)*LDK + h*16];
    kb0 = *(const float4*)(p+0);  kb1 = *(const float4*)(p+4);
    kb2 = *(const float4*)(p+8);  kb3 = *(const float4*)(p+12);
  } else {
    kb0=kb1=kb2=kb3 = make_float4(0.f,0.f,0.f,0.f);
  }
  __syncthreads();

  // ---- V pass: stage, load per-thread fragments ----
  const int cQuad = tid >> 4;   // 0..31 (output quad)
  const int cStrm = tid & 15;   // slot stream
  const int ch    = cQuad >> 2; // head
  cc<12>(encB, Wv, false,  0, 48, sSlotNode, sCE, tid);
  cc<12>(encB, Wv, false, 48, 42, sSlotNode, sCE, tid);
  __syncthreads();
  float4 v0,v1,v2,v3,v4,v5;
  v0 = *(const float4*)&sCE[(cStrm     )*LDK + cQuad*4];
  v1 = *(const float4*)&sCE[(cStrm + 16)*LDK + cQuad*4];
  v2 = *(const float4*)&sCE[(cStrm + 32)*LDK + cQuad*4];
  v3 = *(const float4*)&sCE[(cStrm + 48)*LDK + cQuad*4];
  v4 = *(const float4*)&sCE[(cStrm + 64)*LDK + cQuad*4];
  v5 = (cStrm < 10) ? *(const float4*)&sCE[(cStrm + 80)*LDK + cQuad*4]
                    : make_float4(0.f,0.f,0.f,0.f);
  __syncthreads();

  // ---- CE pass (final home, small RPT to cap pressure) + initial sq ----
  cc<6>(encB, Wcomb, true,  0, 24, sSlotNode, sCE, tid);
  cc<6>(encB, Wcomb, true, 24, 24, sSlotNode, sCE, tid);
  cc<6>(encB, Wcomb, true, 48, 24, sSlotNode, sCE, tid);
  cc<6>(encB, Wcomb, true, 72, 18, sSlotNode, sCE, tid);
  if (grp == 2) sq[col] = qp[22];     // row 90 = last0
  __syncthreads();

  // ---- decode: 90 steps, 4 barriers/step, all operands in regs/LDS ----
  const int di  = tid >> 2;    // phase D slot
  const int dkc = tid & 3;     // phase D k-chunk
  float visA = 0.f, visB = 0.f, visD = 0.f;

  for (int step = 0; step < STEPS; ++step) {
    const int p = step & 1;

    // B: scores vs register K; exp; per-head partition sum
    {
      if (tid == NT-1) sPacked[p] = 0ull;           // reset this step's argmax buffer
      const float4 q0 = *(const float4*)&sq[h*16 + 0];
      const float4 q1 = *(const float4*)&sq[h*16 + 4];
      const float4 q2 = *(const float4*)&sq[h*16 + 8];
      const float4 q3 = *(const float4*)&sq[h*16 + 12];
      float s0 = dot4(q0,ka0)+dot4(q1,ka1)+dot4(q2,ka2)+dot4(q3,ka3);
      float x0 = expf(s0*0.25f + visA);
      sAtt[h*96 + l] = x0;
      float x1 = 0.f;
      if (l < 26) {
        float s1 = dot4(q0,kb0)+dot4(q1,kb1)+dot4(q2,kb2)+dot4(q3,kb3);
        x1 = expf(s1*0.25f + visB);
        sAtt[h*96 + 64 + l] = x1;
      }
      float loc = x0 + x1;
      #pragma unroll
      for (int off = 32; off; off >>= 1) loc += __shfl_xor(loc, off);
      if (l == 0) sSum[h] = loc;
    }
    __syncthreads();

    // C: mh from register V, 16-lane butterfly, per-head normalize
    {
      float4 acc = make_float4(0.f,0.f,0.f,0.f);
      fma4(acc, sAtt[ch*96 + cStrm     ], v0);
      fma4(acc, sAtt[ch*96 + cStrm + 16], v1);
      fma4(acc, sAtt[ch*96 + cStrm + 32], v2);
      fma4(acc, sAtt[ch*96 + cStrm + 48], v3);
      fma4(acc, sAtt[ch*96 + cStrm + 64], v4);
      fma4(acc, sAtt[ch*96 + cStrm + 80], v5);      // v5=0 for cStrm>=10
      #pragma unroll
      for (int off = 1; off < 16; off <<= 1) {
        acc.x += __shfl_xor(acc.x, off);
        acc.y += __shfl_xor(acc.y, off);
        acc.z += __shfl_xor(acc.z, off);
        acc.w += __shfl_xor(acc.w, off);
      }
      if (cStrm == 0) {
        const float r = 1.0f / sSum[ch];
        float4 o; o.x=acc.x*r; o.y=acc.y*r; o.z=acc.z*r; o.w=acc.w*r;
        *(float4*)&sMh[cQuad*4] = o;
      }
    }
    __syncthreads();

    // D: sc[i] = mh . CE_lds[i]; argmax -> packed atomicMax
    if (tid < 384) {
      float a = 0.f;
      #pragma unroll
      for (int j = 0; j < 8; ++j) {
        const float4 ce = *(const float4*)&sCE[di*LDK + dkc*32 + j*4];
        const float4 mh = *(const float4*)&sMh[dkc*32 + j*4];
        a += dot4(ce, mh);
      }
      a += __shfl_xor(a, 1);
      a += __shfl_xor(a, 2);
      float val = (di < S0) ? a + visD : -INFINITY;
      int   idx = (di < S0) ? di : 127;
      #pragma unroll
      for (int off = 32; off; off >>= 1) {
        float ov = __shfl_xor(val, off);
        int   oi = __shfl_xor(idx, off);
        if (ov > val || (ov == val && oi < idx)) { val = ov; idx = oi; }
      }
      if (l == 0) {
        unsigned s = __float_as_uint(val);
        s = (s & 0x80000000u) ? ~s : (s | 0x80000000u);
        unsigned long long pk = ((unsigned long long)s << 32)
                              | (unsigned long long)(unsigned)(127 - idx);
        atomicMax(&sPacked[p], pk);
      }
    }
    __syncthreads();

    // E: broadcast winner; write out; update vis; owners publish next q row
    {
      const unsigned long long u = sPacked[p];
      const int idx = __builtin_amdgcn_readfirstlane(127 - (int)(u & 0xFFull));
      if (tid == 0) out[(size_t)b*N + KL + step] = sSlotNode[idx];
      if (idx == l)      visA = -INFINITY;
      if (idx == l + 64) visB = -INFINITY;
      if (idx == di)     visD = -INFINITY;
      const int want = idx >> 2;            // 0..22, wave-uniform (SGPR)
      float qv = qp[0];
      #pragma unroll
      for (int ii = 1; ii < 23; ++ii) qv = (want == ii) ? qp[ii] : qv;
      if (grp == (idx & 3)) sq[col] = qv;
    }
    __syncthreads();
  }
}

extern "C" void kernel_launch(void* const* d_in, const int* in_sizes, int n_in,
                              void* d_out, int out_size, void* d_ws, size_t ws_size,
                              hipStream_t stream) {
  // inputs: 0 problems (unused), 1 encoded_nodes f32, 2 Wq_first, 3 Wq_last,
  //         4 Wk, 5 Wv, 6 Wcomb, 7 prefix i32
  const float* enc      = (const float*)d_in[1];
  const float* Wq_first = (const float*)d_in[2];
  const float* Wq_last  = (const float*)d_in[3];
  const float* Wk       = (const float*)d_in[4];
  const float* Wv       = (const float*)d_in[5];
  const float* Wcomb    = (const float*)d_in[6];
  const int*   prefix   = (const int*)d_in[7];
  const int batch = in_sizes[7] / KL;   // 2048
  policy_kernel<<<batch, NT, 0, stream>>>(enc, Wq_first, Wq_last, Wk, Wv, Wcomb,
                                          prefix, (int*)d_out);
}